// Round 5
// baseline (640.914 us; speedup 1.0000x reference)
//
#include <hip/hip_runtime.h>
#include <hip/hip_bf16.h>
#include <cstdint>

#define T_STEPS 250
#define BATCH   256
#define NI      700
#define NH      1024
#define NO      20
#define BETAF   0.9f
#define KPAD    704          // 22 * 32
#define KT_N    22
#define KCAT    2112         // 3 * KPAD

typedef __attribute__((ext_vector_type(8))) short bf16x8;
typedef __attribute__((ext_vector_type(4))) float f32x4;
typedef __attribute__((ext_vector_type(8))) unsigned short u16x8;

static __device__ __forceinline__ unsigned short f2bu(float x) {
    union { __hip_bfloat16 h; unsigned short u; } c;
    c.h = __float2bfloat16(x);
    return c.u;
}
static __device__ __forceinline__ float b2f(unsigned short u) {
    union { __hip_bfloat16 h; unsigned short u; } c;
    c.u = u;
    return __bfloat162float(c.h);
}

// ---------------------------------------------------------------------------
// K0: zero LIF state; W2T[h][o]; Bcat = [hi|mid|lo] bf16 split of W1,
//     padded K 700->704. Bcat[n][s*704+k]. 3-split captures 27 mantissa
//     bits -> exact vs fp32 weights; A is binary (bf16-exact).
// ---------------------------------------------------------------------------
__global__ __launch_bounds__(256) void k0_init(const float* __restrict__ W1,
                                               const float* __restrict__ W2,
                                               float* __restrict__ W2T,
                                               float* __restrict__ mem1,
                                               unsigned short* __restrict__ Bcat) {
    int idx = blockIdx.x * 256 + threadIdx.x;
    if (idx < BATCH * NH) mem1[idx] = 0.f;
    if (idx < NH * NO) {
        int h = idx / NO, o = idx % NO;
        W2T[idx] = W2[o * NH + h];
    }
    if (idx < NH * KPAD) {
        int n = idx / KPAD, k = idx % KPAD;
        float w = (k < NI) ? W1[n * NI + k] : 0.f;
        unsigned short hu = f2bu(w);
        float r1 = w - b2f(hu);
        unsigned short mu = f2bu(r1);
        float r2 = r1 - b2f(mu);
        unsigned short lu = f2bu(r2);
        unsigned short* row = Bcat + (size_t)n * KCAT + k;
        row[0]        = hu;
        row[KPAD]     = mu;
        row[2 * KPAD] = lu;
    }
}

// ---------------------------------------------------------------------------
// K2: fc1 via bf16 MFMA, 3-way split, fp32->bf16 cvt FUSED (reads raw
//   spikes), double-buffered LDS, T3-minimum schedule:
//     per iter: [writeA(kt+1); stageB(kt+1); loadA(kt+2); compute(kt); SYNC]
//   The single __syncthreads (vmcnt(0)+lgkmcnt(0)+barrier) is the recipe's
//   "vmcnt(0); barrier" — all staging latency hides under compute.
//   Single-barrier dbuf is race-free: the end-of-iter barrier orders all
//   waves' (lgkm-drained) reads of a buffer before its next overwrite.
//   LDS swizzle as R4 (0 conflicts): phys chunk p of row r holds logical
//   chunk p ^ ((r>>1)&3); B staged linear-dest with pre-swizzled source,
//   A reg-staged with swizzled ds_write. XCD-grouped bid swizzle.
// ---------------------------------------------------------------------------
__global__ __launch_bounds__(256) void k2_fc1(const float* __restrict__ A,
                                              const unsigned short* __restrict__ Bcat,
                                              float* __restrict__ C) {
    __shared__ unsigned short As[2][128 * 32];
    __shared__ unsigned short Bs[2][3][128 * 32];
    const int tid  = threadIdx.x;
    const int lane = tid & 63;
    const int wv   = tid >> 6;

    int nwg = gridDim.x, bid = blockIdx.x, w;
    if ((nwg & 7) == 0) w = (bid & 7) * (nwg >> 3) + (bid >> 3);
    else                w = bid;
    const int brow = (w >> 3) * 128;
    const int bn   = (w & 7) * 128;
    const int wm   = (wv >> 1) * 64;
    const int wn   = (wv & 1) * 64;

    f32x4 acc[4][4];
#pragma unroll
    for (int i = 0; i < 4; ++i)
#pragma unroll
        for (int j = 0; j < 4; ++j) acc[i][j] = (f32x4){0.f, 0.f, 0.f, 0.f};

    // ---- A reg-staging: thread -> (row = tid>>1, k-half = (tid&1)*16) ----
    const int arow = tid >> 1;
    const int ak0  = (tid & 1) * 16;
    const float* arowp = A + (size_t)(brow + arow) * NI;
    float4 ar0, ar1, ar2, ar3;
    auto loadA = [&](int kt) {
        int kg = kt * 32 + ak0;
        ar0 = (kg      < NI) ? *(const float4*)(arowp + kg)      : make_float4(0.f,0.f,0.f,0.f);
        ar1 = (kg + 4  < NI) ? *(const float4*)(arowp + kg + 4)  : make_float4(0.f,0.f,0.f,0.f);
        ar2 = (kg + 8  < NI) ? *(const float4*)(arowp + kg + 8)  : make_float4(0.f,0.f,0.f,0.f);
        ar3 = (kg + 12 < NI) ? *(const float4*)(arowp + kg + 12) : make_float4(0.f,0.f,0.f,0.f);
    };
    const int asw  = (arow >> 1) & 3;
    const int asl0 = ((tid & 1) * 2)     ^ asw;  // phys chunk of logical chunk (tid&1)*2
    const int asl1 = ((tid & 1) * 2 + 1) ^ asw;
    auto writeA = [&](unsigned short* lds) {
        u16x8 lo, hi;
        lo[0] = f2bu(ar0.x); lo[1] = f2bu(ar0.y); lo[2] = f2bu(ar0.z); lo[3] = f2bu(ar0.w);
        lo[4] = f2bu(ar1.x); lo[5] = f2bu(ar1.y); lo[6] = f2bu(ar1.z); lo[7] = f2bu(ar1.w);
        hi[0] = f2bu(ar2.x); hi[1] = f2bu(ar2.y); hi[2] = f2bu(ar2.z); hi[3] = f2bu(ar2.w);
        hi[4] = f2bu(ar3.x); hi[5] = f2bu(ar3.y); hi[6] = f2bu(ar3.z); hi[7] = f2bu(ar3.w);
        *(u16x8*)&lds[arow * 32 + asl0 * 8] = lo;
        *(u16x8*)&lds[arow * 32 + asl1 * 8] = hi;
    };

    // ---- B staging: gload_lds, linear dest, pre-swizzled per-lane source ----
    const unsigned short* Bb = Bcat + (size_t)bn * KCAT;
    auto stageB = [&](int kt, unsigned short (*bs)[128 * 32]) {
#pragma unroll
        for (int s = 0; s < 3; ++s)
#pragma unroll
            for (int j = 0; j < 2; ++j) {
                int c   = wv * 128 + j * 64 + lane;
                int row = c >> 2;
                int lk  = ((c & 3) ^ ((row >> 1) & 3)) * 8;
                const unsigned short* src = Bb + (size_t)row * KCAT + s * KPAD + kt * 32 + lk;
                __builtin_amdgcn_global_load_lds(
                    (const __attribute__((address_space(1))) void*)src,
                    (__attribute__((address_space(3))) void*)(bs[s] + (wv * 128 + j * 64) * 8),
                    16, 0, 0);
            }
    };

    const int frow = lane & 15;
    const int fsl  = (((lane >> 4) & 3) ^ ((frow >> 1) & 3)) * 8;  // swizzled frag slot

    // prologue: fill buffer 0 for kt=0, preload A regs for kt=1
    loadA(0);
    writeA(As[0]);
    stageB(0, Bs[0]);
    loadA(1);
    __syncthreads();   // vmcnt(0)+barrier: buf0 ready

    for (int kt = 0; kt < KT_N; ++kt) {
        const int cur = kt & 1;
        if (kt + 1 < KT_N) {
            writeA(As[cur ^ 1]);          // regs hold A(kt+1)
            stageB(kt + 1, Bs[cur ^ 1]);  // gload_lds issue, drains at end barrier
        }
        if (kt + 2 < KT_N) loadA(kt + 2); // fp32 loads, hide under compute

        const unsigned short* Ac = As[cur];
        bf16x8 a[4];
#pragma unroll
        for (int i = 0; i < 4; ++i)
            a[i] = *(const bf16x8*)&Ac[(wm + i * 16 + frow) * 32 + fsl];
#pragma unroll
        for (int s = 0; s < 3; ++s) {
#pragma unroll
            for (int j = 0; j < 4; ++j) {
                bf16x8 b = *(const bf16x8*)&Bs[cur][s][(wn + j * 16 + frow) * 32 + fsl];
#pragma unroll
                for (int i = 0; i < 4; ++i)
                    acc[i][j] = __builtin_amdgcn_mfma_f32_16x16x32_bf16(a[i], b, acc[i][j], 0, 0, 0);
            }
        }
        __syncthreads();   // vmcnt(0): next tile staged; orders reads before overwrite
    }

    // C/D layout: col = lane&15, row = (lane>>4)*4 + q
#pragma unroll
    for (int i = 0; i < 4; ++i) {
#pragma unroll
        for (int j = 0; j < 4; ++j) {
            int col  = bn + wn + j * 16 + (lane & 15);
            int row0 = brow + wm + i * 16 + ((lane >> 4) << 2);
#pragma unroll
            for (int q = 0; q < 4; ++q)
                C[(size_t)(row0 + q) * NH + col] = acc[i][j][q];
        }
    }
}

// ---------------------------------------------------------------------------
// K3: LIF scan, 4-deep explicit prefetch (named regs, static indexing).
// ---------------------------------------------------------------------------
__global__ __launch_bounds__(256) void k3_lif(const float* __restrict__ cur1,
                                              float* __restrict__ mem1,
                                              unsigned long long* __restrict__ bits,
                                              int TC) {
    int b = blockIdx.x >> 2;
    int hg = blockIdx.x & 3;
    int h = hg * 256 + threadIdx.x;
    const size_t S = (size_t)BATCH * NH;
    const float* p = cur1 + (size_t)b * NH + h;
    unsigned long long* bp = bits + (size_t)b * 16 + hg * 4 + (threadIdx.x >> 6);
    const bool lead = (threadIdx.x & 63) == 0;
    float mem = mem1[b * NH + h];

#define LIF_STEP(cv, t)                                                        \
    {                                                                          \
        float reset = (mem > 1.0f) ? 1.0f : 0.0f;                              \
        mem = fmaf(BETAF, mem, (cv)) - reset;                                  \
        unsigned long long mk = __ballot(mem > 1.0f);                          \
        if (lead) bp[(size_t)(t) * (BATCH * 16)] = mk;                         \
    }

    float c0 = (0 < TC) ? p[0] : 0.f;
    float c1 = (1 < TC) ? p[S] : 0.f;
    float c2 = (2 < TC) ? p[2 * S] : 0.f;
    float c3 = (3 < TC) ? p[3 * S] : 0.f;
    int tc = 0;
    for (; tc + 4 <= TC; tc += 4) {
        LIF_STEP(c0, tc + 0); if (tc + 4 < TC) c0 = p[(size_t)(tc + 4) * S];
        LIF_STEP(c1, tc + 1); if (tc + 5 < TC) c1 = p[(size_t)(tc + 5) * S];
        LIF_STEP(c2, tc + 2); if (tc + 6 < TC) c2 = p[(size_t)(tc + 6) * S];
        LIF_STEP(c3, tc + 3); if (tc + 7 < TC) c3 = p[(size_t)(tc + 7) * S];
    }
    for (; tc < TC; ++tc) { float c = p[(size_t)tc * S]; LIF_STEP(c, tc); }
#undef LIF_STEP
    mem1[b * NH + h] = mem;
}

// ---------------------------------------------------------------------------
// K4: fc2 sparse gather over spike bitmasks. One wave per (t,b) row.
// ---------------------------------------------------------------------------
__global__ __launch_bounds__(256) void k4_fc2(const unsigned long long* __restrict__ bits,
                                              const float* __restrict__ W2T,
                                              float* __restrict__ cur2) {
    int row = blockIdx.x * 4 + (threadIdx.x >> 6);
    int lane = threadIdx.x & 63;
    unsigned long long mv = (lane < 16) ? bits[(size_t)row * 16 + lane] : 0ULL;
    float p = 0.f;
#pragma unroll 1
    for (int wseg = 0; wseg < 16; ++wseg) {
        unsigned long long m = __shfl(mv, wseg);
        while (m) {
            int bit = __ffsll((unsigned long long)m) - 1;
            m &= m - 1;
            int h = wseg * 64 + bit;
            if (lane < NO) p += W2T[h * NO + lane];
        }
    }
    if (lane < NO) cur2[(size_t)row * NO + lane] = p;
}

// ---------------------------------------------------------------------------
// K5: leaky readout + softmax. No max-subtract (|mem| bounded, identical
//     mathematically), one-ahead prefetch, fast exp/div.
// ---------------------------------------------------------------------------
__global__ __launch_bounds__(256) void k5_readout(const float* __restrict__ cur2,
                                                  float* __restrict__ out_mem,
                                                  float* __restrict__ out_sm) {
    int b = blockIdx.x * 8 + (threadIdx.x >> 5);
    int o = threadIdx.x & 31;
    bool act = o < NO;
    const float* p = cur2 + (size_t)b * NO + (act ? o : 0);
    float mem = 0.f;
    float nxt = p[0];
    for (int t = 0; t < T_STEPS; ++t) {
        float c = nxt;
        if (t + 1 < T_STEPS) nxt = p[(size_t)(t + 1) * BATCH * NO];
        mem = fmaf(BETAF, mem, c);
        float e = act ? __expf(mem) : 0.f;
        float s = e;
#pragma unroll
        for (int off = 16; off; off >>= 1) s += __shfl_xor(s, off, 32);
        if (act) {
            int base = (t * BATCH + b) * NO;
            out_mem[base + o] = mem;
            out_sm[base + o] = __fdividef(e, s);
        }
    }
}

// ---------------------------------------------------------------------------
extern "C" void kernel_launch(void* const* d_in, const int* in_sizes, int n_in,
                              void* d_out, int out_size, void* d_ws, size_t ws_size,
                              hipStream_t stream) {
    const float* spikes = (const float*)d_in[0];   // [250,256,700]
    const float* W1     = (const float*)d_in[1];   // [1024,700]
    const float* W2     = (const float*)d_in[2];   // [20,1024]
    float* out_mem = (float*)d_out;                              // [250,256,20]
    float* out_sm  = out_mem + (size_t)T_STEPS * BATCH * NO;     // [250,256,20]

    char* ws = (char*)d_ws;
    size_t off = 0;
    auto alloc = [&](size_t bytes) -> char* {
        off = (off + 255) & ~(size_t)255;
        char* p = ws + off;
        off += bytes;
        return p;
    };
    float*          W2T  = (float*)alloc((size_t)NH * NO * 4);
    float*          mem1 = (float*)alloc((size_t)BATCH * NH * 4);
    float*          cur2 = (float*)alloc((size_t)T_STEPS * BATCH * NO * 4);
    unsigned short* Bcat = (unsigned short*)alloc((size_t)NH * KCAT * 2);

    // T-chunking: per step need cur1 (1 MB) + bits (32 KB).
    size_t fixed = (off + 255) & ~(size_t)255;
    size_t rem = ws_size > fixed ? ws_size - fixed : 0;
    size_t per_t = (size_t)BATCH * NH * 4 + (size_t)BATCH * 16 * 8 + 512;
    int TC = (int)(rem / per_t);
    if (TC > T_STEPS) TC = T_STEPS;
    if (TC < 1) TC = 1;
    float*              cur1 = (float*)alloc((size_t)TC * BATCH * NH * 4);
    unsigned long long* bits = (unsigned long long*)alloc((size_t)TC * BATCH * 16 * 8);

    k0_init<<<(NH * KPAD + 255) / 256, 256, 0, stream>>>(W1, W2, W2T, mem1, Bcat);

    for (int t0 = 0; t0 < T_STEPS; t0 += TC) {
        int tc = T_STEPS - t0 < TC ? T_STEPS - t0 : TC;
        int rows = tc * BATCH;
        int nwg = (rows / 128) * 8;
        k2_fc1<<<nwg, 256, 0, stream>>>(spikes + (size_t)t0 * BATCH * NI, Bcat, cur1);
        k3_lif<<<1024, 256, 0, stream>>>(cur1, mem1, bits, tc);
        k4_fc2<<<tc * 64, 256, 0, stream>>>(bits, W2T, cur2 + (size_t)t0 * BATCH * NO);
    }

    k5_readout<<<32, 256, 0, stream>>>(cur2, out_mem, out_sm);
}

// Round 6
// 601.968 us; speedup vs baseline: 1.0647x; 1.0647x over previous
//
#include <hip/hip_runtime.h>
#include <hip/hip_bf16.h>
#include <cstdint>

#define T_STEPS 250
#define BATCH   256
#define NI      700
#define NH      1024
#define NO      20
#define BETAF   0.9f
#define KPAD    704          // 22 * 32
#define KT_N    22
#define KCAT    2112         // 3 * KPAD

typedef __attribute__((ext_vector_type(8))) short bf16x8;
typedef __attribute__((ext_vector_type(4))) float f32x4;

static __device__ __forceinline__ unsigned short f2bu(float x) {
    union { __hip_bfloat16 h; unsigned short u; } c;
    c.h = __float2bfloat16(x);
    return c.u;
}
static __device__ __forceinline__ float b2f(unsigned short u) {
    union { __hip_bfloat16 h; unsigned short u; } c;
    c.u = u;
    return __bfloat162float(c.h);
}

// ---------------------------------------------------------------------------
// K0: zero LIF state; W2T[h][o]; Bcat = [hi|mid|lo] bf16 split of W1,
//     padded K 700->704. 3-split = 27 mantissa bits -> exact vs fp32.
// ---------------------------------------------------------------------------
__global__ __launch_bounds__(256) void k0_init(const float* __restrict__ W1,
                                               const float* __restrict__ W2,
                                               float* __restrict__ W2T,
                                               float* __restrict__ mem1,
                                               unsigned short* __restrict__ Bcat) {
    int idx = blockIdx.x * 256 + threadIdx.x;
    if (idx < BATCH * NH) mem1[idx] = 0.f;
    if (idx < NH * NO) {
        int h = idx / NO, o = idx % NO;
        W2T[idx] = W2[o * NH + h];
    }
    if (idx < NH * KPAD) {
        int n = idx / KPAD, k = idx % KPAD;
        float w = (k < NI) ? W1[n * NI + k] : 0.f;
        unsigned short hu = f2bu(w);
        float r1 = w - b2f(hu);
        unsigned short mu = f2bu(r1);
        float r2 = r1 - b2f(mu);
        unsigned short lu = f2bu(r2);
        unsigned short* row = Bcat + (size_t)n * KCAT + k;
        row[0]        = hu;
        row[KPAD]     = mu;
        row[2 * KPAD] = lu;
    }
}

// ---------------------------------------------------------------------------
// K1: convert fp32 binary spikes [rows][700] -> bf16 [rows][704] (exact).
// ---------------------------------------------------------------------------
__global__ __launch_bounds__(256) void k1_cvt(const float* __restrict__ A,
                                              unsigned short* __restrict__ Abf,
                                              int rows) {
    int idx = blockIdx.x * 256 + threadIdx.x;   // quad index: 176 per row
    int r = idx / 176, q = idx - r * 176;
    if (r >= rows) return;
    int k = q * 4;
    ushort4 o = make_ushort4(0, 0, 0, 0);
    if (k < NI) {
        float4 v = *(const float4*)(A + (size_t)r * NI + k);
        o.x = f2bu(v.x); o.y = f2bu(v.y); o.z = f2bu(v.z); o.w = f2bu(v.w);
    }
    *(ushort4*)(Abf + (size_t)r * KPAD + k) = o;
}

// ---------------------------------------------------------------------------
// K2: fc1 via bf16 MFMA, 3-way split, DOUBLE-BUFFERED, all staging via
//   global_load_lds from L2-class sources (Abf panels shared per XCD group,
//   Bcat L2-resident). Schedule per iter:
//     [stage(kt+1) -> buf^1 ; ds_read+MFMA on buf ; __syncthreads]
//   The end barrier's vmcnt(0) drains loads that had the whole compute
//   phase (~400cy) to cover ~250cy L2 latency -> ~zero exposure.
//   Race-free: reads of buf^1 finished before the PREVIOUS barrier.
//   LDS swizzle (R4-proven, 0 conflicts): phys chunk p of row r holds
//   logical chunk p ^ ((r>>1)&3); linear dest + pre-swizzled source.
//   XCD-grouped bid swizzle: 8 n-tiles of one m-panel per XCD.
// ---------------------------------------------------------------------------
__global__ __launch_bounds__(256) void k2_fc1(const unsigned short* __restrict__ Abf,
                                              const unsigned short* __restrict__ Bcat,
                                              float* __restrict__ C) {
    __shared__ unsigned short As[2][128 * 32];
    __shared__ unsigned short Bs[2][3][128 * 32];
    const int tid  = threadIdx.x;
    const int lane = tid & 63;
    const int wv   = tid >> 6;

    int nwg = gridDim.x, bid = blockIdx.x, w;
    if ((nwg & 7) == 0) w = (bid & 7) * (nwg >> 3) + (bid >> 3);
    else                w = bid;
    const int brow = (w >> 3) * 128;
    const int bn   = (w & 7) * 128;
    const int wm   = (wv >> 1) * 64;
    const int wn   = (wv & 1) * 64;

    f32x4 acc[4][4];
#pragma unroll
    for (int i = 0; i < 4; ++i)
#pragma unroll
        for (int j = 0; j < 4; ++j) acc[i][j] = (f32x4){0.f, 0.f, 0.f, 0.f};

    // stage one 128x32 bf16 tile: 512 16B chunks; linear LDS dest
    // (wave base + lane*16), per-lane pre-swizzled source column.
    auto stage = [&](const unsigned short* gbase, int rstride, int kcol,
                     unsigned short* lds) {
#pragma unroll
        for (int j = 0; j < 2; ++j) {
            int c   = wv * 128 + j * 64 + lane;
            int row = c >> 2;
            int lk  = ((c & 3) ^ ((row >> 1) & 3)) * 8;
            const unsigned short* src = gbase + (size_t)row * rstride + kcol + lk;
            __builtin_amdgcn_global_load_lds(
                (const __attribute__((address_space(1))) void*)src,
                (__attribute__((address_space(3))) void*)(lds + (wv * 128 + j * 64) * 8),
                16, 0, 0);
        }
    };

    const unsigned short* Ab = Abf + (size_t)brow * KPAD;
    const unsigned short* Bb = Bcat + (size_t)bn * KCAT;

    const int frow = lane & 15;
    const int fsl  = (((lane >> 4) & 3) ^ ((frow >> 1) & 3)) * 8;

    // prologue: fill buffer 0
    stage(Ab, KPAD, 0, As[0]);
#pragma unroll
    for (int s = 0; s < 3; ++s) stage(Bb, KCAT, s * KPAD, Bs[0][s]);
    __syncthreads();

    for (int kt = 0; kt < KT_N; ++kt) {
        const int cur = kt & 1;
        if (kt + 1 < KT_N) {
            stage(Ab, KPAD, (kt + 1) * 32, As[cur ^ 1]);
#pragma unroll
            for (int s = 0; s < 3; ++s)
                stage(Bb, KCAT, s * KPAD + (kt + 1) * 32, Bs[cur ^ 1][s]);
        }

        const unsigned short* Ac = As[cur];
        bf16x8 a[4];
#pragma unroll
        for (int i = 0; i < 4; ++i)
            a[i] = *(const bf16x8*)&Ac[(wm + i * 16 + frow) * 32 + fsl];
#pragma unroll
        for (int s = 0; s < 3; ++s) {
#pragma unroll
            for (int j = 0; j < 4; ++j) {
                bf16x8 b = *(const bf16x8*)&Bs[cur][s][(wn + j * 16 + frow) * 32 + fsl];
#pragma unroll
                for (int i = 0; i < 4; ++i)
                    acc[i][j] = __builtin_amdgcn_mfma_f32_16x16x32_bf16(a[i], b, acc[i][j], 0, 0, 0);
            }
        }
        __syncthreads();   // drains stage(kt+1); orders reads before overwrite
    }

    // C/D layout: col = lane&15, row = (lane>>4)*4 + q
#pragma unroll
    for (int i = 0; i < 4; ++i) {
#pragma unroll
        for (int j = 0; j < 4; ++j) {
            int col  = bn + wn + j * 16 + (lane & 15);
            int row0 = brow + wm + i * 16 + ((lane >> 4) << 2);
#pragma unroll
            for (int q = 0; q < 4; ++q)
                C[(size_t)(row0 + q) * NH + col] = acc[i][j][q];
        }
    }
}

// ---------------------------------------------------------------------------
// K3: LIF scan, 4-deep explicit prefetch (named regs, static indexing).
// ---------------------------------------------------------------------------
__global__ __launch_bounds__(256) void k3_lif(const float* __restrict__ cur1,
                                              float* __restrict__ mem1,
                                              unsigned long long* __restrict__ bits,
                                              int TC) {
    int b = blockIdx.x >> 2;
    int hg = blockIdx.x & 3;
    int h = hg * 256 + threadIdx.x;
    const size_t S = (size_t)BATCH * NH;
    const float* p = cur1 + (size_t)b * NH + h;
    unsigned long long* bp = bits + (size_t)b * 16 + hg * 4 + (threadIdx.x >> 6);
    const bool lead = (threadIdx.x & 63) == 0;
    float mem = mem1[b * NH + h];

#define LIF_STEP(cv, t)                                                        \
    {                                                                          \
        float reset = (mem > 1.0f) ? 1.0f : 0.0f;                              \
        mem = fmaf(BETAF, mem, (cv)) - reset;                                  \
        unsigned long long mk = __ballot(mem > 1.0f);                          \
        if (lead) bp[(size_t)(t) * (BATCH * 16)] = mk;                         \
    }

    float c0 = (0 < TC) ? p[0] : 0.f;
    float c1 = (1 < TC) ? p[S] : 0.f;
    float c2 = (2 < TC) ? p[2 * S] : 0.f;
    float c3 = (3 < TC) ? p[3 * S] : 0.f;
    int tc = 0;
    for (; tc + 4 <= TC; tc += 4) {
        LIF_STEP(c0, tc + 0); if (tc + 4 < TC) c0 = p[(size_t)(tc + 4) * S];
        LIF_STEP(c1, tc + 1); if (tc + 5 < TC) c1 = p[(size_t)(tc + 5) * S];
        LIF_STEP(c2, tc + 2); if (tc + 6 < TC) c2 = p[(size_t)(tc + 6) * S];
        LIF_STEP(c3, tc + 3); if (tc + 7 < TC) c3 = p[(size_t)(tc + 7) * S];
    }
    for (; tc < TC; ++tc) { float c = p[(size_t)tc * S]; LIF_STEP(c, tc); }
#undef LIF_STEP
    mem1[b * NH + h] = mem;
}

// ---------------------------------------------------------------------------
// K4: fc2 sparse gather, 4-wide bit extraction -> 4 independent partial
//     sums (4 L2 loads in flight instead of 1 serial chain).
// ---------------------------------------------------------------------------
__global__ __launch_bounds__(256) void k4_fc2(const unsigned long long* __restrict__ bits,
                                              const float* __restrict__ W2T,
                                              float* __restrict__ cur2) {
    int row = blockIdx.x * 4 + (threadIdx.x >> 6);
    int lane = threadIdx.x & 63;
    bool act = lane < NO;
    unsigned long long mv = (lane < 16) ? bits[(size_t)row * 16 + lane] : 0ULL;
    const float* W = W2T + (act ? lane : 0);
    float p0 = 0.f, p1 = 0.f, p2 = 0.f, p3 = 0.f;
#pragma unroll 1
    for (int wseg = 0; wseg < 16; ++wseg) {
        unsigned long long m = __shfl(mv, wseg);
        int base = wseg * 64;
        while (m) {
            int  b0 = __ffsll(m) - 1;            m &= m - 1;
            bool v1 = m != 0;
            int  b1 = v1 ? __ffsll(m) - 1 : 0;   m &= m - 1;
            bool v2 = m != 0;
            int  b2 = v2 ? __ffsll(m) - 1 : 0;   m &= m - 1;
            bool v3 = m != 0;
            int  b3 = v3 ? __ffsll(m) - 1 : 0;   m &= m - 1;
            float w0 = W[(base + b0) * NO];
            float w1 = W[(base + b1) * NO];
            float w2 = W[(base + b2) * NO];
            float w3 = W[(base + b3) * NO];
            p0 += w0;
            p1 += v1 ? w1 : 0.f;
            p2 += v2 ? w2 : 0.f;
            p3 += v3 ? w3 : 0.f;
        }
    }
    if (act) cur2[(size_t)row * NO + lane] = (p0 + p1) + (p2 + p3);
}

// ---------------------------------------------------------------------------
// K5: leaky readout + softmax (no max-subtract; |mem| bounded), prefetch.
// ---------------------------------------------------------------------------
__global__ __launch_bounds__(256) void k5_readout(const float* __restrict__ cur2,
                                                  float* __restrict__ out_mem,
                                                  float* __restrict__ out_sm) {
    int b = blockIdx.x * 8 + (threadIdx.x >> 5);
    int o = threadIdx.x & 31;
    bool act = o < NO;
    const float* p = cur2 + (size_t)b * NO + (act ? o : 0);
    float mem = 0.f;
    float nxt = p[0];
    for (int t = 0; t < T_STEPS; ++t) {
        float c = nxt;
        if (t + 1 < T_STEPS) nxt = p[(size_t)(t + 1) * BATCH * NO];
        mem = fmaf(BETAF, mem, c);
        float e = act ? __expf(mem) : 0.f;
        float s = e;
#pragma unroll
        for (int off = 16; off; off >>= 1) s += __shfl_xor(s, off, 32);
        if (act) {
            int base = (t * BATCH + b) * NO;
            out_mem[base + o] = mem;
            out_sm[base + o] = __fdividef(e, s);
        }
    }
}

// ---------------------------------------------------------------------------
extern "C" void kernel_launch(void* const* d_in, const int* in_sizes, int n_in,
                              void* d_out, int out_size, void* d_ws, size_t ws_size,
                              hipStream_t stream) {
    const float* spikes = (const float*)d_in[0];   // [250,256,700]
    const float* W1     = (const float*)d_in[1];   // [1024,700]
    const float* W2     = (const float*)d_in[2];   // [20,1024]
    float* out_mem = (float*)d_out;                              // [250,256,20]
    float* out_sm  = out_mem + (size_t)T_STEPS * BATCH * NO;     // [250,256,20]

    char* ws = (char*)d_ws;
    size_t off = 0;
    auto alloc = [&](size_t bytes) -> char* {
        off = (off + 255) & ~(size_t)255;
        char* p = ws + off;
        off += bytes;
        return p;
    };
    float*          W2T  = (float*)alloc((size_t)NH * NO * 4);
    float*          mem1 = (float*)alloc((size_t)BATCH * NH * 4);
    float*          cur2 = (float*)alloc((size_t)T_STEPS * BATCH * NO * 4);
    unsigned short* Bcat = (unsigned short*)alloc((size_t)NH * KCAT * 2);

    // T-chunking: per step need cur1 (1 MB) + Abf (352 KB) + bits (32 KB).
    size_t fixed = (off + 255) & ~(size_t)255;
    size_t rem = ws_size > fixed ? ws_size - fixed : 0;
    size_t per_t = (size_t)BATCH * NH * 4 + (size_t)BATCH * KPAD * 2
                 + (size_t)BATCH * 16 * 8 + 768;
    int TC = (int)(rem / per_t);
    if (TC > T_STEPS) TC = T_STEPS;
    if (TC < 1) TC = 1;
    float*              cur1 = (float*)alloc((size_t)TC * BATCH * NH * 4);
    unsigned short*     Abf  = (unsigned short*)alloc((size_t)TC * BATCH * KPAD * 2);
    unsigned long long* bits = (unsigned long long*)alloc((size_t)TC * BATCH * 16 * 8);

    k0_init<<<(NH * KPAD + 255) / 256, 256, 0, stream>>>(W1, W2, W2T, mem1, Bcat);

    for (int t0 = 0; t0 < T_STEPS; t0 += TC) {
        int tc = T_STEPS - t0 < TC ? T_STEPS - t0 : TC;
        int rows = tc * BATCH;
        k1_cvt<<<(rows * 176 + 255) / 256, 256, 0, stream>>>(
            spikes + (size_t)t0 * BATCH * NI, Abf, rows);
        int nwg = (rows / 128) * 8;
        k2_fc1<<<nwg, 256, 0, stream>>>(Abf, Bcat, cur1);
        k3_lif<<<1024, 256, 0, stream>>>(cur1, mem1, bits, tc);
        k4_fc2<<<tc * 64, 256, 0, stream>>>(bits, W2T, cur2 + (size_t)t0 * BATCH * NO);
    }

    k5_readout<<<32, 256, 0, stream>>>(cur2, out_mem, out_sm);
}